// Round 1
// baseline (3862.424 us; speedup 1.0000x reference)
//
#include <hip/hip_runtime.h>
#include <hip/hip_bf16.h>
#include <math.h>

#define NTOK 1024
#define HID  2048
#define IM   1408
#define NE   32
#define NG   8
#define KG   3
#define TOPK 6
#define ISH  2816
#define NPAIR (NTOK*TOPK)

// ---------------------------------------------------------------------------
// Router: one wave per token. logits = x @ Wg^T, softmax, grouped top-k.
// ---------------------------------------------------------------------------
__global__ __launch_bounds__(64) void router_kernel(
    const float* __restrict__ x, const float* __restrict__ Wg,
    int* __restrict__ tk_id, float* __restrict__ tk_w)
{
    const int t = blockIdx.x;
    const int lane = threadIdx.x;
    __shared__ float sc[NE];
    const float* xr = x + (size_t)t * HID;
    for (int e = 0; e < NE; ++e) {
        const float* wr = Wg + (size_t)e * HID;
        float s = 0.f;
        #pragma unroll 8
        for (int h = lane; h < HID; h += 64) s = fmaf(xr[h], wr[h], s);
        #pragma unroll
        for (int off = 32; off; off >>= 1) s += __shfl_xor(s, off, 64);
        if (lane == 0) sc[e] = s;
    }
    __syncthreads();
    if (lane) return;
    // softmax over 32 logits (serial on lane 0 — trivial)
    float p[NE];
    float mx = sc[0];
    for (int e = 1; e < NE; ++e) mx = fmaxf(mx, sc[e]);
    float sum = 0.f;
    for (int e = 0; e < NE; ++e) { p[e] = expf(sc[e] - mx); sum += p[e]; }
    const float inv = 1.f / sum;
    for (int e = 0; e < NE; ++e) p[e] *= inv;
    // group scores = max prob within each group of 4
    float gs[NG];
    for (int g = 0; g < NG; ++g) {
        float m = p[4*g];
        m = fmaxf(m, p[4*g+1]); m = fmaxf(m, p[4*g+2]); m = fmaxf(m, p[4*g+3]);
        gs[g] = m;
    }
    // top-3 groups (strict > picks lowest index on tie, matching lax.top_k)
    unsigned gmask = 0;
    for (int it = 0; it < KG; ++it) {
        int bi = 0; float bv = -1.f;
        for (int g = 0; g < NG; ++g)
            if (!((gmask >> g) & 1) && gs[g] > bv) { bv = gs[g]; bi = g; }
        gmask |= 1u << bi;
    }
    // top-6 experts among the 12 candidates (probs > 0, so zeros never win)
    unsigned emask = 0;
    for (int it = 0; it < TOPK; ++it) {
        int bi = 0; float bv = -1.f;
        for (int e = 0; e < NE; ++e) {
            if (((emask >> e) & 1) || !((gmask >> (e >> 2)) & 1)) continue;
            if (p[e] > bv) { bv = p[e]; bi = e; }
        }
        emask |= 1u << bi;
        tk_id[t*TOPK + it] = bi;
        tk_w[t*TOPK + it] = bv;   // RENORM == False, SCALE == 1
    }
}

// ---------------------------------------------------------------------------
// Compact: per-expert token lists via count + exclusive scan + scatter.
// ---------------------------------------------------------------------------
__global__ __launch_bounds__(256) void compact_kernel(
    const int* __restrict__ tk_id, const float* __restrict__ tk_w,
    int* __restrict__ cnt, int* __restrict__ off,
    int* __restrict__ tok_list, float* __restrict__ wgt_list)
{
    __shared__ int c[NE], o[NE], pos[NE];
    const int tid = threadIdx.x;
    if (tid < NE) { c[tid] = 0; pos[tid] = 0; }
    __syncthreads();
    for (int i = tid; i < NPAIR; i += 256) atomicAdd(&c[tk_id[i]], 1);
    __syncthreads();
    if (tid == 0) { int run = 0; for (int e = 0; e < NE; ++e) { o[e] = run; run += c[e]; } }
    __syncthreads();
    if (tid < NE) { cnt[tid] = c[tid]; off[tid] = o[tid]; }
    for (int i = tid; i < NPAIR; i += 256) {
        const int e = tk_id[i];
        const int slot = o[e] + atomicAdd(&pos[e], 1);
        tok_list[slot] = i / TOPK;
        wgt_list[slot] = tk_w[i];
    }
}

// XOR swizzle: element (r,k) of a [rows][32] fp32 LDS tile lives at column
// k ^ (((r>>3)&7)<<2)  -> all b128 fragment reads are <=2-way conflicts.
__device__ __forceinline__ int swz_f(int r) { return ((r >> 3) & 7) << 2; }

// ---------------------------------------------------------------------------
// Gate/Up GEMM + fused SiLU*up.  BM=128 tokens x BN=64 h-cols, BK=32.
// 256 thr, micro 8x4 (gate) + 8x4 (up).  GATHER: routed experts.
// ---------------------------------------------------------------------------
template<bool GATHER>
__global__ __launch_bounds__(256) void gu_kernel(
    const float* __restrict__ X, const float* __restrict__ Wbase,
    float* __restrict__ Hout,
    const int* __restrict__ cnt, const int* __restrict__ off,
    const int* __restrict__ tok_list, const int NHALF /* = up offset = ld(Hout) */)
{
    const int e  = blockIdx.z;
    const int n0 = blockIdx.x * 64;
    const int m0 = blockIdx.y * 128;
    int M = NTOK, base = 0;
    if (GATHER) { M = cnt[e]; if (m0 >= M) return; base = off[e]; }
    const float* W = GATHER ? Wbase + (size_t)e * (2*IM) * HID : Wbase;

    __shared__ float As[128*32];
    __shared__ float Bg[64*32];
    __shared__ float Bu[64*32];

    const int tid = threadIdx.x;
    const int rg = tid >> 4, cg = tid & 15;
    const int sr = tid >> 3;          // staging row 0..31
    const int sk = (tid & 7) << 2;    // staging k 0,4..28

    const float* arow[4];
    #pragma unroll
    for (int p = 0; p < 4; ++p) {
        const int m = m0 + sr + p*32;
        int tok;
        if (GATHER) tok = tok_list[base + min(m, M-1)];
        else        tok = m;
        arow[p] = X + (size_t)tok * HID;
    }
    const float *grow[2], *urow[2];
    #pragma unroll
    for (int p = 0; p < 2; ++p) {
        const int r = sr + p*32;
        grow[p] = W + (size_t)(n0 + r) * HID;
        urow[p] = W + (size_t)(NHALF + n0 + r) * HID;
    }

    float accg[8][4] = {{0.f}}, accu[8][4] = {{0.f}};
    const int fa = (rg & 7) << 2;          // swizzle of rows rg*8+i
    const int fb = ((cg >> 1) & 7) << 2;   // swizzle of rows cg*4+j

    for (int k0 = 0; k0 < HID; k0 += 32) {
        #pragma unroll
        for (int p = 0; p < 4; ++p) {
            const int r = sr + p*32;
            *(float4*)&As[r*32 + (sk ^ swz_f(r))] = *(const float4*)(arow[p] + k0 + sk);
        }
        #pragma unroll
        for (int p = 0; p < 2; ++p) {
            const int r = sr + p*32;
            const int col = sk ^ swz_f(r);
            *(float4*)&Bg[r*32 + col] = *(const float4*)(grow[p] + k0 + sk);
            *(float4*)&Bu[r*32 + col] = *(const float4*)(urow[p] + k0 + sk);
        }
        __syncthreads();
        #pragma unroll
        for (int k4 = 0; k4 < 8; ++k4) {
            const int ia = (k4 << 2) ^ fa;
            const int ib = (k4 << 2) ^ fb;
            float4 a4[8];
            #pragma unroll
            for (int i = 0; i < 8; ++i) a4[i] = *(const float4*)&As[(rg*8+i)*32 + ia];
            #pragma unroll
            for (int j = 0; j < 4; ++j) {
                const float4 g4 = *(const float4*)&Bg[(cg*4+j)*32 + ib];
                const float4 u4 = *(const float4*)&Bu[(cg*4+j)*32 + ib];
                #pragma unroll
                for (int i = 0; i < 8; ++i) {
                    accg[i][j] = fmaf(a4[i].x, g4.x, accg[i][j]);
                    accg[i][j] = fmaf(a4[i].y, g4.y, accg[i][j]);
                    accg[i][j] = fmaf(a4[i].z, g4.z, accg[i][j]);
                    accg[i][j] = fmaf(a4[i].w, g4.w, accg[i][j]);
                    accu[i][j] = fmaf(a4[i].x, u4.x, accu[i][j]);
                    accu[i][j] = fmaf(a4[i].y, u4.y, accu[i][j]);
                    accu[i][j] = fmaf(a4[i].z, u4.z, accu[i][j]);
                    accu[i][j] = fmaf(a4[i].w, u4.w, accu[i][j]);
                }
            }
        }
        __syncthreads();
    }
    #pragma unroll
    for (int i = 0; i < 8; ++i) {
        const int m = m0 + rg*8 + i;
        if (m >= M) continue;
        float4 hv;
        {
            const float g0 = accg[i][0], g1 = accg[i][1], g2 = accg[i][2], g3 = accg[i][3];
            hv.x = g0 / (1.f + expf(-g0)) * accu[i][0];
            hv.y = g1 / (1.f + expf(-g1)) * accu[i][1];
            hv.z = g2 / (1.f + expf(-g2)) * accu[i][2];
            hv.w = g3 / (1.f + expf(-g3)) * accu[i][3];
        }
        *(float4*)&Hout[(size_t)(base + m) * NHALF + n0 + cg*4] = hv;
    }
}

// ---------------------------------------------------------------------------
// Down GEMM.  BM=128 x BN=128, BK=32, micro 8x8.
// ROUTED: atomicAdd into out with per-pair weight; else plain store.
// ---------------------------------------------------------------------------
template<bool ROUTED>
__global__ __launch_bounds__(256) void down_kernel(
    const float* __restrict__ Hin, const float* __restrict__ Wbase,
    float* __restrict__ Out,
    const int* __restrict__ cnt, const int* __restrict__ off,
    const int* __restrict__ tok_list, const float* __restrict__ wgt_list,
    const int KD)
{
    const int e  = blockIdx.z;
    const int c0 = blockIdx.x * 128;
    const int m0 = blockIdx.y * 128;
    int M = NTOK, base = 0;
    if (ROUTED) { M = cnt[e]; if (m0 >= M) return; base = off[e]; }
    const float* W = ROUTED ? Wbase + (size_t)e * HID * IM : Wbase;

    __shared__ float As[128*32];
    __shared__ float Bs[128*32];

    const int tid = threadIdx.x;
    const int rg = tid >> 4, cg = tid & 15;
    const int sr = tid >> 3;
    const int sk = (tid & 7) << 2;

    const float *arow[4], *brow[4];
    #pragma unroll
    for (int p = 0; p < 4; ++p) {
        const int m = m0 + sr + p*32;
        arow[p] = Hin + (size_t)(base + min(m, M-1)) * KD;
        brow[p] = W + (size_t)(c0 + sr + p*32) * KD;
    }
    float acc[8][8] = {{0.f}};
    const int fa = (rg & 7) << 2;
    const int fb = (cg & 7) << 2;

    for (int k0 = 0; k0 < KD; k0 += 32) {
        #pragma unroll
        for (int p = 0; p < 4; ++p) {
            const int r = sr + p*32;
            const int col = sk ^ swz_f(r);
            *(float4*)&As[r*32 + col] = *(const float4*)(arow[p] + k0 + sk);
            *(float4*)&Bs[r*32 + col] = *(const float4*)(brow[p] + k0 + sk);
        }
        __syncthreads();
        #pragma unroll
        for (int k4 = 0; k4 < 8; ++k4) {
            const int ia = (k4 << 2) ^ fa;
            const int ib = (k4 << 2) ^ fb;
            float4 a4[8];
            #pragma unroll
            for (int i = 0; i < 8; ++i) a4[i] = *(const float4*)&As[(rg*8+i)*32 + ia];
            #pragma unroll
            for (int j = 0; j < 8; ++j) {
                const float4 b4 = *(const float4*)&Bs[(cg*8+j)*32 + ib];
                #pragma unroll
                for (int i = 0; i < 8; ++i) {
                    acc[i][j] = fmaf(a4[i].x, b4.x, acc[i][j]);
                    acc[i][j] = fmaf(a4[i].y, b4.y, acc[i][j]);
                    acc[i][j] = fmaf(a4[i].z, b4.z, acc[i][j]);
                    acc[i][j] = fmaf(a4[i].w, b4.w, acc[i][j]);
                }
            }
        }
        __syncthreads();
    }
    #pragma unroll
    for (int i = 0; i < 8; ++i) {
        const int m = m0 + rg*8 + i;
        if (m >= M) continue;
        if (ROUTED) {
            const int tok  = tok_list[base + m];
            const float w  = wgt_list[base + m];
            float* orow = Out + (size_t)tok * HID + c0 + cg*8;
            #pragma unroll
            for (int j = 0; j < 8; ++j) atomicAdd(&orow[j], acc[i][j] * w);
        } else {
            float* orow = Out + (size_t)m * HID + c0 + cg*8;
            float4 v0 = {acc[i][0], acc[i][1], acc[i][2], acc[i][3]};
            float4 v1 = {acc[i][4], acc[i][5], acc[i][6], acc[i][7]};
            *(float4*)&orow[0] = v0;
            *(float4*)&orow[4] = v1;
        }
    }
}

// ---------------------------------------------------------------------------
extern "C" void kernel_launch(void* const* d_in, const int* in_sizes, int n_in,
                              void* d_out, int out_size, void* d_ws, size_t ws_size,
                              hipStream_t stream)
{
    const float* x     = (const float*)d_in[0];
    const float* Wg    = (const float*)d_in[1];
    const float* Wgu   = (const float*)d_in[2];
    const float* Wd    = (const float*)d_in[3];
    const float* Wgu_s = (const float*)d_in[4];
    const float* Wd_s  = (const float*)d_in[5];
    float* out = (float*)d_out;

    char* ws = (char*)d_ws;
    size_t o = 0;
    auto alloc = [&](size_t bytes) -> void* {
        void* p = ws + o;
        o = (o + bytes + 255) & ~(size_t)255;
        return p;
    };
    int*   cnt      = (int*)  alloc(NE * 4);
    int*   off      = (int*)  alloc(NE * 4);
    int*   tk_id    = (int*)  alloc(NPAIR * 4);
    float* tk_w     = (float*)alloc(NPAIR * 4);
    int*   tok_list = (int*)  alloc(NPAIR * 4);
    float* wgt_list = (float*)alloc(NPAIR * 4);
    float* h_r      = (float*)alloc((size_t)NPAIR * IM * 4);   // 34.6 MB
    float* h_s      = (float*)alloc((size_t)NTOK * ISH * 4);   // 11.5 MB

    router_kernel<<<dim3(NTOK), dim3(64), 0, stream>>>(x, Wg, tk_id, tk_w);
    compact_kernel<<<dim3(1), dim3(256), 0, stream>>>(tk_id, tk_w, cnt, off, tok_list, wgt_list);
    // shared expert (writes every element of d_out; must precede routed atomics)
    gu_kernel<false><<<dim3(ISH/64, NTOK/128, 1), dim3(256), 0, stream>>>(
        x, Wgu_s, h_s, nullptr, nullptr, nullptr, ISH);
    down_kernel<false><<<dim3(HID/128, NTOK/128, 1), dim3(256), 0, stream>>>(
        h_s, Wd_s, out, nullptr, nullptr, nullptr, nullptr, ISH);
    // routed experts
    gu_kernel<true><<<dim3(IM/64, NTOK/128, NE), dim3(256), 0, stream>>>(
        x, Wgu, h_r, cnt, off, tok_list, IM);
    down_kernel<true><<<dim3(HID/128, NTOK/128, NE), dim3(256), 0, stream>>>(
        h_r, Wd, out, cnt, off, tok_list, wgt_list, IM);
}